// Round 1
// 697.622 us; speedup vs baseline: 1.0639x; 1.0639x over previous
//
#include <hip/hip_runtime.h>

// Problem constants (B=8, S=200, H=4, D=64, HID=256) — all tensors fp32.
#define SB 8
#define SS 200
#define HID 256
#define NH 4
#define DH 64

typedef float f32x4_t __attribute__((ext_vector_type(4)));

__device__ __forceinline__ float4 ntload4(const float* p) {
    f32x4_t v = __builtin_nontemporal_load((const f32x4_t*)p);
    return make_float4(v.x, v.y, v.z, v.w);
}

// ---------------------------------------------------------------------------
// Kernel 1: fused projections + row-dot scalars.
//   q = in@Wq+bq ; k = in@Wk+bk ; kpk = k+posK ; vpv = in@Wv+bv+posV
//   qo/qd = per-(row,head) dots of q with order_w[:64]/dist_w[:64]
//   ko/kd = per-(row,head) dots of k with order_w[64:]/dist_w[64:]
// grid (200, 3), block 256. 8 rows per block, 2x4 register tile per thread.
// ---------------------------------------------------------------------------
__global__ __launch_bounds__(256) void proj_fused_kernel(
    const float* __restrict__ in,
    const float* __restrict__ Wq, const float* __restrict__ bq,
    const float* __restrict__ Wk, const float* __restrict__ bk,
    const float* __restrict__ Wv, const float* __restrict__ bv,
    const float* __restrict__ posK, const float* __restrict__ posV,
    const float* __restrict__ order_w, const float* __restrict__ dist_w,
    float* __restrict__ q_out, float* __restrict__ kpk_out,
    float* __restrict__ vpv_out,
    float* __restrict__ qo, float* __restrict__ ko,
    float* __restrict__ qd, float* __restrict__ kd)
{
    const int which = blockIdx.y;
    const float* W = (which == 0) ? Wq : (which == 1) ? Wk : Wv;
    const float* bias = (which == 0) ? bq : (which == 1) ? bk : bv;
    const int row0 = blockIdx.x * 8;
    __shared__ float sin_[8][HID];
    const int t = threadIdx.x;
    #pragma unroll
    for (int r = 0; r < 8; r++)
        sin_[r][t] = in[(size_t)(row0 + r) * HID + t];
    __syncthreads();

    const int tx = t & 63, ty = t >> 6;
    const int c0 = tx * 4, r0 = ty * 2;
    float acc[2][4] = {};
    #pragma unroll 4
    for (int kk = 0; kk < HID; kk++) {
        const float4 wv4 = *(const float4*)(W + (size_t)kk * HID + c0);
        const float a0 = sin_[r0][kk];
        const float a1 = sin_[r0 + 1][kk];
        acc[0][0] += a0 * wv4.x; acc[0][1] += a0 * wv4.y;
        acc[0][2] += a0 * wv4.z; acc[0][3] += a0 * wv4.w;
        acc[1][0] += a1 * wv4.x; acc[1][1] += a1 * wv4.y;
        acc[1][2] += a1 * wv4.z; acc[1][3] += a1 * wv4.w;
    }

    const float4 b4 = *(const float4*)(bias + c0);
    const int hh = tx >> 4;           // head of this lane's column range
    const int dd4 = (tx & 15) * 4;    // dim-within-head of this lane's cols
    float4 ow4 = make_float4(0.f, 0.f, 0.f, 0.f);
    float4 dw4 = make_float4(0.f, 0.f, 0.f, 0.f);
    if (which == 0) {
        ow4 = *(const float4*)(order_w + dd4);
        dw4 = *(const float4*)(dist_w + dd4);
    } else if (which == 1) {
        ow4 = *(const float4*)(order_w + 64 + dd4);
        dw4 = *(const float4*)(dist_w + 64 + dd4);
    }

    #pragma unroll
    for (int rr = 0; rr < 2; rr++) {
        const int row = row0 + r0 + rr;
        const size_t off = (size_t)row * HID + c0;
        float4 o;
        o.x = acc[rr][0] + b4.x;
        o.y = acc[rr][1] + b4.y;
        o.z = acc[rr][2] + b4.z;
        o.w = acc[rr][3] + b4.w;
        if (which == 0) {
            *(float4*)(q_out + off) = o;
            float po = o.x * ow4.x + o.y * ow4.y + o.z * ow4.z + o.w * ow4.w;
            float pd = o.x * dw4.x + o.y * dw4.y + o.z * dw4.z + o.w * dw4.w;
            #pragma unroll
            for (int m = 1; m <= 8; m <<= 1) {
                po += __shfl_xor(po, m, 64);
                pd += __shfl_xor(pd, m, 64);
            }
            if ((tx & 15) == 0) {
                qo[row * NH + hh] = po;
                qd[row * NH + hh] = pd;
            }
        } else if (which == 1) {
            const float4 p4 = *(const float4*)(posK + off);
            float4 s;
            s.x = o.x + p4.x; s.y = o.y + p4.y;
            s.z = o.z + p4.z; s.w = o.w + p4.w;
            *(float4*)(kpk_out + off) = s;
            float po = o.x * ow4.x + o.y * ow4.y + o.z * ow4.z + o.w * ow4.w;
            float pd = o.x * dw4.x + o.y * dw4.y + o.z * dw4.z + o.w * dw4.w;
            #pragma unroll
            for (int m = 1; m <= 8; m <<= 1) {
                po += __shfl_xor(po, m, 64);
                pd += __shfl_xor(pd, m, 64);
            }
            if ((tx & 15) == 0) {
                ko[row * NH + hh] = po;
                kd[row * NH + hh] = pd;
            }
        } else {
            const float4 p4 = *(const float4*)(posV + off);
            float4 s;
            s.x = o.x + p4.x; s.y = o.y + p4.y;
            s.z = o.z + p4.z; s.w = o.w + p4.w;
            *(float4*)(vpv_out + off) = s;
        }
    }
}

// ---------------------------------------------------------------------------
// Kernel 2: fused attention + out-projection + residual + LayerNorm.
// One block per (b,i), 256 threads = 4 waves. Wave w handles j-rows j0+w.
// Pre-phase: error-order/dist + mask for all (h,j) -> sh_e (no divergent
//            transcendentals in the streaming loops).
// Pass 1 (x2 unroll): scores; softmax per head (wave w = head w).
// Pass 2 (x2 unroll): ctx accumulate.
// Epilogue: hs = ctx@Wd + bd + input; LayerNorm; write final output.
// timeK/timeV are single-use streams -> nontemporal loads (keep kpk/vpv/Wd
// resident in L2).
// ---------------------------------------------------------------------------
__global__ __launch_bounds__(256) void attn_fused_kernel(
    const float* __restrict__ q, const float* __restrict__ kpk,
    const float* __restrict__ vpv,
    const float* __restrict__ timeK, const float* __restrict__ timeV,
    const float* __restrict__ mask,
    const float* __restrict__ qo, const float* __restrict__ ko,
    const float* __restrict__ qd, const float* __restrict__ kd,
    const float* __restrict__ order_b_p, const float* __restrict__ dist_b_p,
    const float* __restrict__ scalar_p,
    const float* __restrict__ Wd, const float* __restrict__ bd,
    const float* __restrict__ input,
    const float* __restrict__ ln_g, const float* __restrict__ ln_b,
    float* __restrict__ out)
{
    const int blk = blockIdx.x;
    const int b = blk / SS, i = blk - b * SS;
    const int t = threadIdx.x;
    const int w = t >> 6, l = t & 63;
    const int h = l >> 4;           // head handled by this lane in passes
    const int sub = l & 15;         // 16 lanes per head

    __shared__ float sh_q[HID];
    __shared__ float sh_e[NH][SS + 8];
    __shared__ float sh_s[NH][SS + 8];
    __shared__ float sh_red[4][HID];
    __shared__ float sh_c[HID];
    __shared__ float red2[4];

    const size_t rowq = (size_t)blk * HID;
    sh_q[t] = q[rowq + t];

    // ---- Pre-phase: (eo + ed) * 0.125 + mask for all (h,j), dense ----
    const float order_b = *order_b_p;
    const float dist_b = *dist_b_p;
    const float sc = *scalar_p;
    const float sc2h = 0.5f * sc * sc;
    const size_t tb = (size_t)blk * SS;   // row base into [B*S, S] tables
    for (int idx = t; idx < NH * SS; idx += 256) {
        const int eh = idx & 3, j = idx >> 2;
        const float xo = qo[blk * NH + eh] + ko[(b * SS + j) * NH + eh] + order_b;
        const float pr = 1.0f / (1.0f + __expf(-xo));
        const float eo = (j > i) ? __logf(pr + 1e-24f) : __logf(1.0f - pr + 1e-24f);
        const float xd = qd[blk * NH + eh] + kd[(b * SS + j) * NH + eh] + dist_b;
        const float gd = __logf(fabsf((float)(i - j)) + 1.0f);
        const float dv = gd - xd;
        sh_e[eh][j] = (eo - dv * dv * sc2h) * 0.125f + mask[tb + j];
    }
    __syncthreads();

    const int d0 = l * 4;           // element range [d0, d0+4) == head h dims
    const float4 qr = *(const float4*)(sh_q + d0);

    // ---- Pass 1: scores (unroll x2 -> 4 loads in flight/wave) ----
    for (int j0 = 0; j0 < SS; j0 += 8) {
        const int ja = j0 + w, jb = ja + 4;
        const float4 ta = ntload4(timeK + (tb + ja) * (size_t)HID + d0);
        const float4 tb4 = ntload4(timeK + (tb + jb) * (size_t)HID + d0);
        const float4 ka = *(const float4*)(kpk + ((size_t)(b * SS + ja)) * HID + d0);
        const float4 kb = *(const float4*)(kpk + ((size_t)(b * SS + jb)) * HID + d0);
        float pa = (ta.x + ka.x) * qr.x + (ta.y + ka.y) * qr.y
                 + (ta.z + ka.z) * qr.z + (ta.w + ka.w) * qr.w;
        float pb = (tb4.x + kb.x) * qr.x + (tb4.y + kb.y) * qr.y
                 + (tb4.z + kb.z) * qr.z + (tb4.w + kb.w) * qr.w;
        pa += __shfl_xor(pa, 1, 64); pb += __shfl_xor(pb, 1, 64);
        pa += __shfl_xor(pa, 2, 64); pb += __shfl_xor(pb, 2, 64);
        pa += __shfl_xor(pa, 4, 64); pb += __shfl_xor(pb, 4, 64);
        pa += __shfl_xor(pa, 8, 64); pb += __shfl_xor(pb, 8, 64);
        if (sub == 0) {
            sh_s[h][ja] = pa * 0.125f + sh_e[h][ja];
            sh_s[h][jb] = pb * 0.125f + sh_e[h][jb];
        }
    }
    __syncthreads();

    // ---- Softmax: wave w handles head w ----
    {
        float vals[4];
        float m = -1e30f;
        #pragma unroll
        for (int rep = 0; rep < 4; rep++) {
            const int j = l + rep * 64;
            vals[rep] = (j < SS) ? sh_s[w][j] : -1e30f;
            m = fmaxf(m, vals[rep]);
        }
        #pragma unroll
        for (int mm = 32; mm >= 1; mm >>= 1) m = fmaxf(m, __shfl_xor(m, mm, 64));
        float sum = 0.0f;
        float es[4];
        #pragma unroll
        for (int rep = 0; rep < 4; rep++) {
            const int j = l + rep * 64;
            if (j < SS) { es[rep] = __expf(vals[rep] - m); sum += es[rep]; }
        }
        #pragma unroll
        for (int mm = 32; mm >= 1; mm >>= 1) sum += __shfl_xor(sum, mm, 64);
        const float inv = 1.0f / sum;
        #pragma unroll
        for (int rep = 0; rep < 4; rep++) {
            const int j = l + rep * 64;
            if (j < SS) sh_s[w][j] = es[rep] * inv;
        }
    }
    __syncthreads();

    // ---- Pass 2: context (unroll x2) ----
    float4 acc = make_float4(0.f, 0.f, 0.f, 0.f);
    for (int j0 = 0; j0 < SS; j0 += 8) {
        const int ja = j0 + w, jb = ja + 4;
        const float4 ta = ntload4(timeV + (tb + ja) * (size_t)HID + d0);
        const float4 tb4 = ntload4(timeV + (tb + jb) * (size_t)HID + d0);
        const float4 va = *(const float4*)(vpv + ((size_t)(b * SS + ja)) * HID + d0);
        const float4 vb = *(const float4*)(vpv + ((size_t)(b * SS + jb)) * HID + d0);
        const float pa = sh_s[h][ja];
        const float pb = sh_s[h][jb];
        acc.x += pa * (ta.x + va.x) + pb * (tb4.x + vb.x);
        acc.y += pa * (ta.y + va.y) + pb * (tb4.y + vb.y);
        acc.z += pa * (ta.z + va.z) + pb * (tb4.z + vb.z);
        acc.w += pa * (ta.w + va.w) + pb * (tb4.w + vb.w);
    }
    *(float4*)(&sh_red[w][d0]) = acc;
    __syncthreads();
    sh_c[t] = sh_red[0][t] + sh_red[1][t] + sh_red[2][t] + sh_red[3][t];
    __syncthreads();

    // ---- Epilogue: out-projection + residual ----
    float hsv = bd[t] + input[rowq + t];
    #pragma unroll 4
    for (int kk = 0; kk < HID; kk++)
        hsv += sh_c[kk] * Wd[(size_t)kk * HID + t];

    // ---- LayerNorm over the 256 columns of this row ----
    float s = hsv;
    #pragma unroll
    for (int m = 32; m >= 1; m >>= 1) s += __shfl_xor(s, m, 64);
    if (l == 0) red2[w] = s;
    __syncthreads();
    const float mu = (red2[0] + red2[1] + red2[2] + red2[3]) * (1.0f / 256.0f);
    __syncthreads();
    const float dv = hsv - mu;
    float s2 = dv * dv;
    #pragma unroll
    for (int m = 32; m >= 1; m >>= 1) s2 += __shfl_xor(s2, m, 64);
    if (l == 0) red2[w] = s2;
    __syncthreads();
    const float var = (red2[0] + red2[1] + red2[2] + red2[3]) * (1.0f / 256.0f);
    out[rowq + t] = dv * rsqrtf(var + 1e-12f) * ln_g[t] + ln_b[t];
}

// ---------------------------------------------------------------------------
extern "C" void kernel_launch(void* const* d_in, const int* in_sizes, int n_in,
                              void* d_out, int out_size, void* d_ws, size_t ws_size,
                              hipStream_t stream) {
    const float* input   = (const float*)d_in[0];
    const float* mask    = (const float*)d_in[1];
    const float* posK    = (const float*)d_in[2];
    const float* posV    = (const float*)d_in[3];
    const float* timeK   = (const float*)d_in[4];
    const float* timeV   = (const float*)d_in[5];
    const float* Wq      = (const float*)d_in[6];
    const float* bq      = (const float*)d_in[7];
    const float* Wk      = (const float*)d_in[8];
    const float* bk      = (const float*)d_in[9];
    const float* Wv      = (const float*)d_in[10];
    const float* bv      = (const float*)d_in[11];
    const float* order_w = (const float*)d_in[12];
    const float* order_b = (const float*)d_in[13];
    const float* dist_w  = (const float*)d_in[14];
    const float* dist_b  = (const float*)d_in[15];
    const float* scalar  = (const float*)d_in[16];
    const float* Wd      = (const float*)d_in[17];
    const float* bd      = (const float*)d_in[18];
    const float* ln_g    = (const float*)d_in[19];
    const float* ln_b    = (const float*)d_in[20];

    const int NROW = SB * SS;          // 1600
    float* ws = (float*)d_ws;
    float* q_ws   = ws;                 // 409600
    float* kpk_ws = q_ws   + 409600;
    float* vpv_ws = kpk_ws + 409600;
    float* qo_ws  = vpv_ws + 409600;    // 6400 each
    float* ko_ws  = qo_ws  + 6400;
    float* qd_ws  = ko_ws  + 6400;
    float* kd_ws  = qd_ws  + 6400;      // ~5.0 MB total

    proj_fused_kernel<<<dim3(NROW / 8, 3), 256, 0, stream>>>(
        input, Wq, bq, Wk, bk, Wv, bv, posK, posV, order_w, dist_w,
        q_ws, kpk_ws, vpv_ws, qo_ws, ko_ws, qd_ws, kd_ws);
    attn_fused_kernel<<<NROW, 256, 0, stream>>>(
        q_ws, kpk_ws, vpv_ws, timeK, timeV, mask,
        qo_ws, ko_ws, qd_ws, kd_ws, order_b, dist_b, scalar,
        Wd, bd, input, ln_g, ln_b, (float*)d_out);
}

// Round 2
// 692.696 us; speedup vs baseline: 1.0714x; 1.0071x over previous
//
#include <hip/hip_runtime.h>

// Problem constants (B=8, S=200, H=4, D=64, HID=256) — all tensors fp32.
#define SB 8
#define SS 200
#define HID 256
#define NH 4
#define DH 64

typedef float f32x4_t __attribute__((ext_vector_type(4)));

__device__ __forceinline__ float4 ntload4(const float* p) {
    f32x4_t v = __builtin_nontemporal_load((const f32x4_t*)p);
    return make_float4(v.x, v.y, v.z, v.w);
}

// ---------------------------------------------------------------------------
// Kernel 1: fused projections + row-dot scalars.
//   q = in@Wq+bq ; k = in@Wk+bk ; kpk = k+posK ; vpv = in@Wv+bv+posV
//   qo/qd = per-(row,head) dots of q with order_w[:64]/dist_w[:64]
//   ko/kd = per-(row,head) dots of k with order_w[64:]/dist_w[64:]
// grid (200, 3), block 256. 8 rows per block, 2x4 register tile per thread.
// ---------------------------------------------------------------------------
__global__ __launch_bounds__(256) void proj_fused_kernel(
    const float* __restrict__ in,
    const float* __restrict__ Wq, const float* __restrict__ bq,
    const float* __restrict__ Wk, const float* __restrict__ bk,
    const float* __restrict__ Wv, const float* __restrict__ bv,
    const float* __restrict__ posK, const float* __restrict__ posV,
    const float* __restrict__ order_w, const float* __restrict__ dist_w,
    float* __restrict__ q_out, float* __restrict__ kpk_out,
    float* __restrict__ vpv_out,
    float* __restrict__ qo, float* __restrict__ ko,
    float* __restrict__ qd, float* __restrict__ kd)
{
    const int which = blockIdx.y;
    const float* W = (which == 0) ? Wq : (which == 1) ? Wk : Wv;
    const float* bias = (which == 0) ? bq : (which == 1) ? bk : bv;
    const int row0 = blockIdx.x * 8;
    __shared__ float sin_[8][HID];
    const int t = threadIdx.x;
    #pragma unroll
    for (int r = 0; r < 8; r++)
        sin_[r][t] = in[(size_t)(row0 + r) * HID + t];
    __syncthreads();

    const int tx = t & 63, ty = t >> 6;
    const int c0 = tx * 4, r0 = ty * 2;
    float acc[2][4] = {};
    #pragma unroll 4
    for (int kk = 0; kk < HID; kk++) {
        const float4 wv4 = *(const float4*)(W + (size_t)kk * HID + c0);
        const float a0 = sin_[r0][kk];
        const float a1 = sin_[r0 + 1][kk];
        acc[0][0] += a0 * wv4.x; acc[0][1] += a0 * wv4.y;
        acc[0][2] += a0 * wv4.z; acc[0][3] += a0 * wv4.w;
        acc[1][0] += a1 * wv4.x; acc[1][1] += a1 * wv4.y;
        acc[1][2] += a1 * wv4.z; acc[1][3] += a1 * wv4.w;
    }

    const float4 b4 = *(const float4*)(bias + c0);
    const int hh = tx >> 4;           // head of this lane's column range
    const int dd4 = (tx & 15) * 4;    // dim-within-head of this lane's cols
    float4 ow4 = make_float4(0.f, 0.f, 0.f, 0.f);
    float4 dw4 = make_float4(0.f, 0.f, 0.f, 0.f);
    if (which == 0) {
        ow4 = *(const float4*)(order_w + dd4);
        dw4 = *(const float4*)(dist_w + dd4);
    } else if (which == 1) {
        ow4 = *(const float4*)(order_w + 64 + dd4);
        dw4 = *(const float4*)(dist_w + 64 + dd4);
    }

    #pragma unroll
    for (int rr = 0; rr < 2; rr++) {
        const int row = row0 + r0 + rr;
        const size_t off = (size_t)row * HID + c0;
        float4 o;
        o.x = acc[rr][0] + b4.x;
        o.y = acc[rr][1] + b4.y;
        o.z = acc[rr][2] + b4.z;
        o.w = acc[rr][3] + b4.w;
        if (which == 0) {
            *(float4*)(q_out + off) = o;
            float po = o.x * ow4.x + o.y * ow4.y + o.z * ow4.z + o.w * ow4.w;
            float pd = o.x * dw4.x + o.y * dw4.y + o.z * dw4.z + o.w * dw4.w;
            #pragma unroll
            for (int m = 1; m <= 8; m <<= 1) {
                po += __shfl_xor(po, m, 64);
                pd += __shfl_xor(pd, m, 64);
            }
            if ((tx & 15) == 0) {
                qo[row * NH + hh] = po;
                qd[row * NH + hh] = pd;
            }
        } else if (which == 1) {
            const float4 p4 = *(const float4*)(posK + off);
            float4 s;
            s.x = o.x + p4.x; s.y = o.y + p4.y;
            s.z = o.z + p4.z; s.w = o.w + p4.w;
            *(float4*)(kpk_out + off) = s;
            float po = o.x * ow4.x + o.y * ow4.y + o.z * ow4.z + o.w * ow4.w;
            float pd = o.x * dw4.x + o.y * dw4.y + o.z * dw4.z + o.w * dw4.w;
            #pragma unroll
            for (int m = 1; m <= 8; m <<= 1) {
                po += __shfl_xor(po, m, 64);
                pd += __shfl_xor(pd, m, 64);
            }
            if ((tx & 15) == 0) {
                ko[row * NH + hh] = po;
                kd[row * NH + hh] = pd;
            }
        } else {
            const float4 p4 = *(const float4*)(posV + off);
            float4 s;
            s.x = o.x + p4.x; s.y = o.y + p4.y;
            s.z = o.z + p4.z; s.w = o.w + p4.w;
            *(float4*)(vpv_out + off) = s;
        }
    }
}

// ---------------------------------------------------------------------------
// Kernel 2: fused attention + out-projection + residual + LayerNorm.
// One block per (b,i), 256 threads = 4 waves. Wave w handles j-rows j0+w+4s.
// Pass 1 (x4 unroll, 8 loads in flight/wave): raw scores -> sh_s.
// Pre-phase AFTER pass1 (overlaps stream tail): error-order/dist + mask
//            -> sh_e, wave w handles head w.
// Softmax per head (wave w = head w), consumes sh_s + sh_e.
// Pass 2 (x4 unroll): ctx accumulate.
// Epilogue: hs = ctx@Wd + bd + input (vectorized float4 GEMV, wave-split
//           over kk), then LayerNorm, write final output.
// timeK/timeV are single-use streams -> nontemporal loads (keep kpk/vpv/Wd
// resident in L2).
// ---------------------------------------------------------------------------
__global__ __launch_bounds__(256) void attn_fused_kernel(
    const float* __restrict__ q, const float* __restrict__ kpk,
    const float* __restrict__ vpv,
    const float* __restrict__ timeK, const float* __restrict__ timeV,
    const float* __restrict__ mask,
    const float* __restrict__ qo, const float* __restrict__ ko,
    const float* __restrict__ qd, const float* __restrict__ kd,
    const float* __restrict__ order_b_p, const float* __restrict__ dist_b_p,
    const float* __restrict__ scalar_p,
    const float* __restrict__ Wd, const float* __restrict__ bd,
    const float* __restrict__ input,
    const float* __restrict__ ln_g, const float* __restrict__ ln_b,
    float* __restrict__ out)
{
    const int blk = blockIdx.x;
    const int b = blk / SS, i = blk - b * SS;
    const int t = threadIdx.x;
    const int w = t >> 6, l = t & 63;
    const int h = l >> 4;           // head handled by this lane in passes
    const int sub = l & 15;         // 16 lanes per head

    __shared__ float sh_q[HID];
    __shared__ float sh_e[NH][SS + 8];
    __shared__ float sh_s[NH][SS + 8];
    __shared__ float sh_red[4][HID];
    __shared__ float sh_c[HID];
    __shared__ float red2[4];

    const size_t rowq = (size_t)blk * HID;
    sh_q[t] = q[rowq + t];
    __syncthreads();

    const int d0 = l * 4;           // element range [d0, d0+4) == head h dims
    const float4 qr = *(const float4*)(sh_q + d0);
    const size_t tb = (size_t)blk * SS;   // row base into [B*S, S] tables
    const float* __restrict__ kpkb = kpk + (size_t)b * SS * HID;
    const float* __restrict__ vpvb = vpv + (size_t)b * SS * HID;

    // ---- Pass 1: raw scores, x4 unroll, 8 loads in flight per wave ----
    for (int j0 = 0; j0 < 192; j0 += 16) {
        const int ja = j0 + w;
        const float4 t0 = ntload4(timeK + (tb + ja)      * (size_t)HID + d0);
        const float4 t1 = ntload4(timeK + (tb + ja + 4)  * (size_t)HID + d0);
        const float4 t2 = ntload4(timeK + (tb + ja + 8)  * (size_t)HID + d0);
        const float4 t3 = ntload4(timeK + (tb + ja + 12) * (size_t)HID + d0);
        const float4 k0 = *(const float4*)(kpkb + (size_t)(ja)      * HID + d0);
        const float4 k1 = *(const float4*)(kpkb + (size_t)(ja + 4)  * HID + d0);
        const float4 k2 = *(const float4*)(kpkb + (size_t)(ja + 8)  * HID + d0);
        const float4 k3 = *(const float4*)(kpkb + (size_t)(ja + 12) * HID + d0);
        float p0 = (t0.x + k0.x) * qr.x + (t0.y + k0.y) * qr.y
                 + (t0.z + k0.z) * qr.z + (t0.w + k0.w) * qr.w;
        float p1 = (t1.x + k1.x) * qr.x + (t1.y + k1.y) * qr.y
                 + (t1.z + k1.z) * qr.z + (t1.w + k1.w) * qr.w;
        float p2 = (t2.x + k2.x) * qr.x + (t2.y + k2.y) * qr.y
                 + (t2.z + k2.z) * qr.z + (t2.w + k2.w) * qr.w;
        float p3 = (t3.x + k3.x) * qr.x + (t3.y + k3.y) * qr.y
                 + (t3.z + k3.z) * qr.z + (t3.w + k3.w) * qr.w;
        #pragma unroll
        for (int m = 1; m <= 8; m <<= 1) {
            p0 += __shfl_xor(p0, m, 64);
            p1 += __shfl_xor(p1, m, 64);
            p2 += __shfl_xor(p2, m, 64);
            p3 += __shfl_xor(p3, m, 64);
        }
        if (sub == 0) {
            sh_s[h][ja]      = p0 * 0.125f;
            sh_s[h][ja + 4]  = p1 * 0.125f;
            sh_s[h][ja + 8]  = p2 * 0.125f;
            sh_s[h][ja + 12] = p3 * 0.125f;
        }
    }
    {   // tail: j = 192..199
        const int ja = 192 + w, jb = 196 + w;
        const float4 t0 = ntload4(timeK + (tb + ja) * (size_t)HID + d0);
        const float4 t1 = ntload4(timeK + (tb + jb) * (size_t)HID + d0);
        const float4 k0 = *(const float4*)(kpkb + (size_t)ja * HID + d0);
        const float4 k1 = *(const float4*)(kpkb + (size_t)jb * HID + d0);
        float p0 = (t0.x + k0.x) * qr.x + (t0.y + k0.y) * qr.y
                 + (t0.z + k0.z) * qr.z + (t0.w + k0.w) * qr.w;
        float p1 = (t1.x + k1.x) * qr.x + (t1.y + k1.y) * qr.y
                 + (t1.z + k1.z) * qr.z + (t1.w + k1.w) * qr.w;
        #pragma unroll
        for (int m = 1; m <= 8; m <<= 1) {
            p0 += __shfl_xor(p0, m, 64);
            p1 += __shfl_xor(p1, m, 64);
        }
        if (sub == 0) {
            sh_s[h][ja] = p0 * 0.125f;
            sh_s[h][jb] = p1 * 0.125f;
        }
    }

    // ---- Pre-phase (overlaps pass-1 tail): wave w handles head w ----
    {
        const float order_b = *order_b_p;
        const float dist_b = *dist_b_p;
        const float sc = *scalar_p;
        const float sc2h = 0.5f * sc * sc;
        const float qo_w = qo[blk * NH + w];
        const float qd_w = qd[blk * NH + w];
        for (int j = l; j < SS; j += 64) {
            const float xo = qo_w + ko[(b * SS + j) * NH + w] + order_b;
            const float pr = 1.0f / (1.0f + __expf(-xo));
            const float eo = (j > i) ? __logf(pr + 1e-24f)
                                     : __logf(1.0f - pr + 1e-24f);
            const float xd = qd_w + kd[(b * SS + j) * NH + w] + dist_b;
            const float gd = __logf(fabsf((float)(i - j)) + 1.0f);
            const float dv = gd - xd;
            sh_e[w][j] = (eo - dv * dv * sc2h) * 0.125f + mask[tb + j];
        }
    }
    __syncthreads();

    // ---- Softmax: wave w handles head w; consumes sh_s + sh_e ----
    {
        float vals[4];
        float m = -1e30f;
        #pragma unroll
        for (int rep = 0; rep < 4; rep++) {
            const int j = l + rep * 64;
            vals[rep] = (j < SS) ? (sh_s[w][j] + sh_e[w][j]) : -1e30f;
            m = fmaxf(m, vals[rep]);
        }
        #pragma unroll
        for (int mm = 32; mm >= 1; mm >>= 1) m = fmaxf(m, __shfl_xor(m, mm, 64));
        float sum = 0.0f;
        float es[4];
        #pragma unroll
        for (int rep = 0; rep < 4; rep++) {
            const int j = l + rep * 64;
            if (j < SS) { es[rep] = __expf(vals[rep] - m); sum += es[rep]; }
        }
        #pragma unroll
        for (int mm = 32; mm >= 1; mm >>= 1) sum += __shfl_xor(sum, mm, 64);
        const float inv = 1.0f / sum;
        #pragma unroll
        for (int rep = 0; rep < 4; rep++) {
            const int j = l + rep * 64;
            if (j < SS) sh_s[w][j] = es[rep] * inv;
        }
    }
    __syncthreads();

    // ---- Pass 2: context, x4 unroll ----
    float4 acc = make_float4(0.f, 0.f, 0.f, 0.f);
    for (int j0 = 0; j0 < 192; j0 += 16) {
        const int ja = j0 + w;
        const float4 t0 = ntload4(timeV + (tb + ja)      * (size_t)HID + d0);
        const float4 t1 = ntload4(timeV + (tb + ja + 4)  * (size_t)HID + d0);
        const float4 t2 = ntload4(timeV + (tb + ja + 8)  * (size_t)HID + d0);
        const float4 t3 = ntload4(timeV + (tb + ja + 12) * (size_t)HID + d0);
        const float4 v0 = *(const float4*)(vpvb + (size_t)(ja)      * HID + d0);
        const float4 v1 = *(const float4*)(vpvb + (size_t)(ja + 4)  * HID + d0);
        const float4 v2 = *(const float4*)(vpvb + (size_t)(ja + 8)  * HID + d0);
        const float4 v3 = *(const float4*)(vpvb + (size_t)(ja + 12) * HID + d0);
        const float p0 = sh_s[h][ja];
        const float p1 = sh_s[h][ja + 4];
        const float p2 = sh_s[h][ja + 8];
        const float p3 = sh_s[h][ja + 12];
        acc.x += p0 * (t0.x + v0.x) + p1 * (t1.x + v1.x)
               + p2 * (t2.x + v2.x) + p3 * (t3.x + v3.x);
        acc.y += p0 * (t0.y + v0.y) + p1 * (t1.y + v1.y)
               + p2 * (t2.y + v2.y) + p3 * (t3.y + v3.y);
        acc.z += p0 * (t0.z + v0.z) + p1 * (t1.z + v1.z)
               + p2 * (t2.z + v2.z) + p3 * (t3.z + v3.z);
        acc.w += p0 * (t0.w + v0.w) + p1 * (t1.w + v1.w)
               + p2 * (t2.w + v2.w) + p3 * (t3.w + v3.w);
    }
    {   // tail: j = 192..199
        const int ja = 192 + w, jb = 196 + w;
        const float4 t0 = ntload4(timeV + (tb + ja) * (size_t)HID + d0);
        const float4 t1 = ntload4(timeV + (tb + jb) * (size_t)HID + d0);
        const float4 v0 = *(const float4*)(vpvb + (size_t)ja * HID + d0);
        const float4 v1 = *(const float4*)(vpvb + (size_t)jb * HID + d0);
        const float p0 = sh_s[h][ja];
        const float p1 = sh_s[h][jb];
        acc.x += p0 * (t0.x + v0.x) + p1 * (t1.x + v1.x);
        acc.y += p0 * (t0.y + v0.y) + p1 * (t1.y + v1.y);
        acc.z += p0 * (t0.z + v0.z) + p1 * (t1.z + v1.z);
        acc.w += p0 * (t0.w + v0.w) + p1 * (t1.w + v1.w);
    }
    *(float4*)(&sh_red[w][d0]) = acc;
    __syncthreads();
    sh_c[t] = sh_red[0][t] + sh_red[1][t] + sh_red[2][t] + sh_red[3][t];
    __syncthreads();

    // ---- Epilogue GEMV: wave w covers kk in [64w, 64w+64), cols l*4 ----
    {
        float4 a = make_float4(0.f, 0.f, 0.f, 0.f);
        const int kbase = w * 64;
        #pragma unroll 4
        for (int kk = 0; kk < 64; kk += 4) {
            const float4 c4 = *(const float4*)(sh_c + kbase + kk);
            const float4 w0 = *(const float4*)(Wd + (size_t)(kbase + kk)     * HID + d0);
            const float4 w1 = *(const float4*)(Wd + (size_t)(kbase + kk + 1) * HID + d0);
            const float4 w2 = *(const float4*)(Wd + (size_t)(kbase + kk + 2) * HID + d0);
            const float4 w3 = *(const float4*)(Wd + (size_t)(kbase + kk + 3) * HID + d0);
            a.x += c4.x * w0.x + c4.y * w1.x + c4.z * w2.x + c4.w * w3.x;
            a.y += c4.x * w0.y + c4.y * w1.y + c4.z * w2.y + c4.w * w3.y;
            a.z += c4.x * w0.z + c4.y * w1.z + c4.z * w2.z + c4.w * w3.z;
            a.w += c4.x * w0.w + c4.y * w1.w + c4.z * w2.w + c4.w * w3.w;
        }
        *(float4*)(&sh_red[w][d0]) = a;
    }
    __syncthreads();

    const float hsv = sh_red[0][t] + sh_red[1][t] + sh_red[2][t] + sh_red[3][t]
                    + bd[t] + input[rowq + t];

    // ---- LayerNorm over the 256 columns of this row ----
    float s = hsv;
    #pragma unroll
    for (int m = 32; m >= 1; m >>= 1) s += __shfl_xor(s, m, 64);
    if (l == 0) red2[w] = s;
    __syncthreads();
    const float mu = (red2[0] + red2[1] + red2[2] + red2[3]) * (1.0f / 256.0f);
    __syncthreads();
    const float dv = hsv - mu;
    float s2 = dv * dv;
    #pragma unroll
    for (int m = 32; m >= 1; m >>= 1) s2 += __shfl_xor(s2, m, 64);
    if (l == 0) red2[w] = s2;
    __syncthreads();
    const float var = (red2[0] + red2[1] + red2[2] + red2[3]) * (1.0f / 256.0f);
    out[rowq + t] = dv * rsqrtf(var + 1e-12f) * ln_g[t] + ln_b[t];
}

// ---------------------------------------------------------------------------
extern "C" void kernel_launch(void* const* d_in, const int* in_sizes, int n_in,
                              void* d_out, int out_size, void* d_ws, size_t ws_size,
                              hipStream_t stream) {
    const float* input   = (const float*)d_in[0];
    const float* mask    = (const float*)d_in[1];
    const float* posK    = (const float*)d_in[2];
    const float* posV    = (const float*)d_in[3];
    const float* timeK   = (const float*)d_in[4];
    const float* timeV   = (const float*)d_in[5];
    const float* Wq      = (const float*)d_in[6];
    const float* bq      = (const float*)d_in[7];
    const float* Wk      = (const float*)d_in[8];
    const float* bk      = (const float*)d_in[9];
    const float* Wv      = (const float*)d_in[10];
    const float* bv      = (const float*)d_in[11];
    const float* order_w = (const float*)d_in[12];
    const float* order_b = (const float*)d_in[13];
    const float* dist_w  = (const float*)d_in[14];
    const float* dist_b  = (const float*)d_in[15];
    const float* scalar  = (const float*)d_in[16];
    const float* Wd      = (const float*)d_in[17];
    const float* bd      = (const float*)d_in[18];
    const float* ln_g    = (const float*)d_in[19];
    const float* ln_b    = (const float*)d_in[20];

    const int NROW = SB * SS;          // 1600
    float* ws = (float*)d_ws;
    float* q_ws   = ws;                 // 409600
    float* kpk_ws = q_ws   + 409600;
    float* vpv_ws = kpk_ws + 409600;
    float* qo_ws  = vpv_ws + 409600;    // 6400 each
    float* ko_ws  = qo_ws  + 6400;
    float* qd_ws  = ko_ws  + 6400;
    float* kd_ws  = qd_ws  + 6400;      // ~5.0 MB total

    proj_fused_kernel<<<dim3(NROW / 8, 3), 256, 0, stream>>>(
        input, Wq, bq, Wk, bk, Wv, bv, posK, posV, order_w, dist_w,
        q_ws, kpk_ws, vpv_ws, qo_ws, ko_ws, qd_ws, kd_ws);
    attn_fused_kernel<<<NROW, 256, 0, stream>>>(
        q_ws, kpk_ws, vpv_ws, timeK, timeV, mask,
        qo_ws, ko_ws, qd_ws, kd_ws, order_b, dist_b, scalar,
        Wd, bd, input, ln_g, ln_b, (float*)d_out);
}